// Round 1
// baseline (417.469 us; speedup 1.0000x reference)
//
#include <hip/hip_runtime.h>
#include <hip/hip_bf16.h>

#define NB 2
#define NL 2048
#define ND 1024
#define NH 16
#define NDT 64

typedef unsigned short u16;
typedef unsigned int u32;

typedef __attribute__((ext_vector_type(8))) short s16x8;
typedef __attribute__((ext_vector_type(4))) float f32x4;
typedef __attribute__((ext_vector_type(4))) u16 u16x4;
typedef __attribute__((ext_vector_type(4))) u32 u32x4;

// f32 -> bf16 (RNE)
static __device__ __forceinline__ u16 f2b(float f) {
  union { float f; u32 u; } x; x.f = f;
  u32 r = x.u + 0x7fffu + ((x.u >> 16) & 1u);
  return (u16)(r >> 16);
}

// XOR-swizzled byte offset within a 64x64 bf16 tile (128B rows)
static __device__ __forceinline__ int swz(int r, int cb) {
  return r * 128 + (cb ^ ((r & 7) << 4));
}

// ---------------------------------------------------------------------------
// Generic GEMM: out[m][n] = sum_k A[m][k] * W[n][k] + bias[n]
// MODE 0: write bf16 at (b,h,l,d)   [q,k projections]
// MODE 1: write bf16 at (b,h,d,l)   [v projection, transposed]
// MODE 2: write f32 at (m,n)        [final projection]
// ---------------------------------------------------------------------------
template<typename TA, int MODE>
__global__ __launch_bounds__(256)
void gemm_k(const TA* __restrict__ A, const float* __restrict__ W,
            const float* __restrict__ bias, void* __restrict__ outp,
            int M, int N, int K)
{
  __shared__ __align__(16) u16 lA[64 * 64];
  __shared__ __align__(16) u16 lB[64 * 64];
  const int tid = threadIdx.x;
  const int lane = tid & 63, wid = tid >> 6;
  const int wm = wid >> 1, wn = wid & 1;
  const int lrow = lane & 15, lgrp = lane >> 4;
  const int mbase = blockIdx.y * 64, nbase = blockIdx.x * 64;

  f32x4 acc[2][2] = {};

  for (int k0 = 0; k0 < K; k0 += 64) {
#pragma unroll
    for (int i = 0; i < 4; ++i) {
      int e = i * 1024 + tid * 4;
      int r = e >> 6, c = e & 63;
      u16x4 av;
      if constexpr (sizeof(TA) == 4) {
        f32x4 v = *reinterpret_cast<const f32x4*>(A + (size_t)(mbase + r) * K + k0 + c);
        av[0] = f2b(v[0]); av[1] = f2b(v[1]); av[2] = f2b(v[2]); av[3] = f2b(v[3]);
      } else {
        av = *reinterpret_cast<const u16x4*>(A + (size_t)(mbase + r) * K + k0 + c);
      }
      *reinterpret_cast<u16x4*>((char*)lA + swz(r, c * 2)) = av;

      f32x4 wv = *reinterpret_cast<const f32x4*>(W + (size_t)(nbase + r) * K + k0 + c);
      u16x4 bv2; bv2[0] = f2b(wv[0]); bv2[1] = f2b(wv[1]); bv2[2] = f2b(wv[2]); bv2[3] = f2b(wv[3]);
      *reinterpret_cast<u16x4*>((char*)lB + swz(r, c * 2)) = bv2;
    }
    __syncthreads();

#pragma unroll
    for (int ks = 0; ks < 2; ++ks) {
      s16x8 af[2], bf[2];
#pragma unroll
      for (int t = 0; t < 2; ++t) {
        af[t] = *reinterpret_cast<const s16x8*>((char*)lA + swz(wm * 32 + t * 16 + lrow, ks * 64 + lgrp * 16));
        bf[t] = *reinterpret_cast<const s16x8*>((char*)lB + swz(wn * 32 + t * 16 + lrow, ks * 64 + lgrp * 16));
      }
#pragma unroll
      for (int mt = 0; mt < 2; ++mt)
#pragma unroll
        for (int nt = 0; nt < 2; ++nt)
          acc[mt][nt] = __builtin_amdgcn_mfma_f32_16x16x32_bf16(af[mt], bf[nt], acc[mt][nt], 0, 0, 0);
    }
    __syncthreads();
  }

  // epilogue: D layout is col=lane&15, row=(lane>>4)*4+reg
#pragma unroll
  for (int mt = 0; mt < 2; ++mt) {
#pragma unroll
    for (int nt = 0; nt < 2; ++nt) {
      int n = nbase + wn * 32 + nt * 16 + lrow;
      float bv = bias[n];
      int m0 = mbase + wm * 32 + mt * 16 + lgrp * 4;
      f32x4 a = acc[mt][nt];
      if constexpr (MODE == 1) {
        int b = m0 >> 11, l0 = m0 & 2047;
        int h = n >> 6, d = n & 63;
        u16x4 ov;
#pragma unroll
        for (int rg = 0; rg < 4; ++rg) ov[rg] = f2b(a[rg] + bv);
        *reinterpret_cast<u16x4*>((u16*)outp + ((size_t)((b * NH + h) * NDT + d)) * NL + l0) = ov;
      } else {
#pragma unroll
        for (int rg = 0; rg < 4; ++rg) {
          int m = m0 + rg;
          float val = a[rg] + bv;
          if constexpr (MODE == 0) {
            int b = m >> 11, l = m & 2047;
            int h = n >> 6, d = n & 63;
            ((u16*)outp)[((size_t)((b * NH + h) * NL + l)) * NDT + d] = f2b(val);
          } else {
            ((float*)outp)[(size_t)m * N + n] = val;
          }
        }
      }
    }
  }
}

// ---------------------------------------------------------------------------
// Flash attention: block = (b, h, 64 q-rows); 4 waves x 16 q-rows each.
// q,k: (B*H, L, 64) bf16; vt: (B*H, 64, L) bf16; ao: (B*L, 1024) bf16.
// ---------------------------------------------------------------------------
__global__ __launch_bounds__(256)
void attn_k(const u16* __restrict__ q, const u16* __restrict__ k,
            const u16* __restrict__ vt, const int* __restrict__ mask,
            const float* __restrict__ bias, u16* __restrict__ ao)
{
  __shared__ __align__(16) u16 kl[64 * 64];
  __shared__ __align__(16) u16 vl[64 * 64];
  __shared__ __align__(16) u16 pl[4 * 16 * 64];

  const int tid = threadIdx.x;
  const int lane = tid & 63, w = tid >> 6;
  const int bid = blockIdx.x;
  const int h = bid & (NH - 1);
  const int b = (bid >> 4) & (NB - 1);
  const int qt = bid >> 5;
  const int bh = b * NH + h;
  const int qbase = qt * 64;
  const int lrow = lane & 15, lgrp = lane >> 4;

  // Q fragments (A-operand layout): row=lane&15, kdim=(lane>>4)*8+j
  const int qrow = qbase + w * 16 + lrow;
  s16x8 qf[2];
#pragma unroll
  for (int ks = 0; ks < 2; ++ks)
    qf[ks] = *reinterpret_cast<const s16x8*>(q + ((size_t)bh * NL + qrow) * NDT + ks * 32 + lgrp * 8);

  f32x4 o[4] = {};
  float mrun[4], lrun[4];
#pragma unroll
  for (int rg = 0; rg < 4; ++rg) { mrun[rg] = -1e30f; lrun[rg] = 0.f; }

  const float scale = 0.125f; // 1/sqrt(64)
  u16* pw = pl + w * 16 * 64;

  for (int kk = 0; kk < NL; kk += 64) {
    // stage K-tile (rows=kpos, cols=d) and V-tile (rows=d, cols=kpos)
#pragma unroll
    for (int i = 0; i < 2; ++i) {
      int e = i * 2048 + tid * 8;
      int r = e >> 6, c = e & 63;
      *reinterpret_cast<u32x4*>((char*)kl + swz(r, c * 2)) =
          *reinterpret_cast<const u32x4*>(k + ((size_t)bh * NL + kk + r) * NDT + c);
      *reinterpret_cast<u32x4*>((char*)vl + swz(r, c * 2)) =
          *reinterpret_cast<const u32x4*>(vt + ((size_t)bh * NDT + r) * NL + kk + c);
    }
    __syncthreads();

    // S = q . k^T  (16 q-rows x 64 k-cols per wave)
    float sv[4][4];
#pragma unroll
    for (int nt = 0; nt < 4; ++nt) {
      f32x4 s = {};
#pragma unroll
      for (int ks = 0; ks < 2; ++ks) {
        s16x8 kf = *reinterpret_cast<const s16x8*>((char*)kl + swz(nt * 16 + lrow, ks * 64 + lgrp * 16));
        s = __builtin_amdgcn_mfma_f32_16x16x32_bf16(qf[ks], kf, s, 0, 0, 0);
      }
#pragma unroll
      for (int rg = 0; rg < 4; ++rg) sv[nt][rg] = s[rg];
    }

    // scale, mask, bias  (value at row=lgrp*4+rg, col=nt*16+lrow)
#pragma unroll
    for (int nt = 0; nt < 4; ++nt) {
      int kcol = kk + nt * 16 + lrow;
#pragma unroll
      for (int rg = 0; rg < 4; ++rg) {
        int qr = qbase + w * 16 + lgrp * 4 + rg;
        int mz = mask[((size_t)b * NL + qr) * NL + kcol];
        float bz = bias[((size_t)h * NL + qr) * NL + kcol];
        float val = sv[nt][rg] * scale;
        val = (mz == 0 ? -10000.0f : val) + bz;
        sv[nt][rg] = val;
      }
    }

    // online softmax: rows live in 16-lane groups -> xor-shuffle reduce
    float mnew[4], alpha[4], rs[4];
#pragma unroll
    for (int rg = 0; rg < 4; ++rg) {
      float mx = fmaxf(fmaxf(sv[0][rg], sv[1][rg]), fmaxf(sv[2][rg], sv[3][rg]));
#pragma unroll
      for (int off = 1; off < 16; off <<= 1)
        mx = fmaxf(mx, __shfl_xor(mx, off));
      mnew[rg] = fmaxf(mrun[rg], mx);
      alpha[rg] = __expf(mrun[rg] - mnew[rg]);
      mrun[rg] = mnew[rg];
      rs[rg] = 0.f;
    }
#pragma unroll
    for (int nt = 0; nt < 4; ++nt)
#pragma unroll
      for (int rg = 0; rg < 4; ++rg) {
        float p = __expf(sv[nt][rg] - mnew[rg]);
        sv[nt][rg] = p;
        rs[rg] += p;
      }
#pragma unroll
    for (int rg = 0; rg < 4; ++rg) {
      float s = rs[rg];
#pragma unroll
      for (int off = 1; off < 16; off <<= 1) s += __shfl_xor(s, off);
      lrun[rg] = lrun[rg] * alpha[rg] + s;
#pragma unroll
      for (int dt = 0; dt < 4; ++dt) o[dt][rg] *= alpha[rg];
    }

    // P -> per-wave LDS (transpose into A-operand layout)
#pragma unroll
    for (int nt = 0; nt < 4; ++nt)
#pragma unroll
      for (int rg = 0; rg < 4; ++rg) {
        int r = lgrp * 4 + rg, cc = nt * 16 + lrow;
        *reinterpret_cast<u16*>((char*)pw + swz(r, cc * 2)) = f2b(sv[nt][rg]);
      }

    // PV: o[q][d] += P[q][kpos] * V[kpos][d]
    s16x8 pa[2];
#pragma unroll
    for (int ks = 0; ks < 2; ++ks)
      pa[ks] = *reinterpret_cast<const s16x8*>((char*)pw + swz(lrow, ks * 64 + lgrp * 16));
#pragma unroll
    for (int dt = 0; dt < 4; ++dt) {
#pragma unroll
      for (int ks = 0; ks < 2; ++ks) {
        s16x8 vf = *reinterpret_cast<const s16x8*>((char*)vl + swz(dt * 16 + lrow, ks * 64 + lgrp * 16));
        o[dt] = __builtin_amdgcn_mfma_f32_16x16x32_bf16(pa[ks], vf, o[dt], 0, 0, 0);
      }
    }
    __syncthreads();
  }

  // normalize + write attention output (bf16, (b,l,h*64+d))
#pragma unroll
  for (int rg = 0; rg < 4; ++rg) {
    float inv = 1.0f / lrun[rg];
    int qr = qbase + w * 16 + lgrp * 4 + rg;
#pragma unroll
    for (int dt = 0; dt < 4; ++dt) {
      int d = dt * 16 + lrow;
      ao[((size_t)(b * NL + qr)) * ND + h * NDT + d] = f2b(o[dt][rg] * inv);
    }
  }
}

extern "C" void kernel_launch(void* const* d_in, const int* in_sizes, int n_in,
                              void* d_out, int out_size, void* d_ws, size_t ws_size,
                              hipStream_t stream)
{
  const float* Q    = (const float*)d_in[0];
  const float* K    = (const float*)d_in[1];
  const float* V    = (const float*)d_in[2];
  const int*   mask = (const int*)d_in[3];
  const float* bias = (const float*)d_in[4];
  const float* Wq   = (const float*)d_in[5];
  const float* bq   = (const float*)d_in[6];
  const float* Wk   = (const float*)d_in[7];
  const float* bk   = (const float*)d_in[8];
  const float* Wv   = (const float*)d_in[9];
  const float* bv   = (const float*)d_in[10];
  const float* Wo   = (const float*)d_in[11];
  const float* bo   = (const float*)d_in[12];

  u16* qb  = (u16*)d_ws;
  u16* kb  = qb  + (size_t)NB * NH * NL * NDT;
  u16* vtb = kb  + (size_t)NB * NH * NL * NDT;
  u16* aob = vtb + (size_t)NB * NH * NL * NDT;

  dim3 blk(256);
  dim3 gproj(ND / 64, (NB * NL) / 64);

  gemm_k<float, 0><<<gproj, blk, 0, stream>>>(Q, Wq, bq, qb,  NB * NL, ND, ND);
  gemm_k<float, 0><<<gproj, blk, 0, stream>>>(K, Wk, bk, kb,  NB * NL, ND, ND);
  gemm_k<float, 1><<<gproj, blk, 0, stream>>>(V, Wv, bv, vtb, NB * NL, ND, ND);

  attn_k<<<dim3(NB * NH * (NL / 64)), blk, 0, stream>>>(qb, kb, vtb, mask, bias, aob);

  gemm_k<u16, 2><<<gproj, blk, 0, stream>>>(aob, Wo, bo, d_out, NB * NL, ND, ND);
}

// Round 2
// 410.020 us; speedup vs baseline: 1.0182x; 1.0182x over previous
//
#include <hip/hip_runtime.h>
#include <hip/hip_bf16.h>

#define NB 2
#define NL 2048
#define ND 1024
#define NH 16
#define NDT 64

typedef unsigned short u16;
typedef unsigned int u32;
typedef unsigned long long u64;

typedef __attribute__((ext_vector_type(8))) short s16x8;
typedef __attribute__((ext_vector_type(4))) float f32x4;
typedef __attribute__((ext_vector_type(4))) u16 u16x4;
typedef __attribute__((ext_vector_type(8))) u16 u16x8;

// f32 -> bf16 (RNE)
static __device__ __forceinline__ u16 f2b(float f) {
  union { float f; u32 u; } x; x.f = f;
  u32 r = x.u + 0x7fffu + ((x.u >> 16) & 1u);
  return (u16)(r >> 16);
}

// XOR-swizzled byte offset within a [rows][64] bf16 tile (128B rows)
static __device__ __forceinline__ int swz(int r, int cb) {
  return r * 128 + (cb ^ ((r & 7) << 4));
}

// async global->LDS 16B (dest: wave-uniform base + lane*16)
static __device__ __forceinline__ void gl16(const void* g, void* l) {
  __builtin_amdgcn_global_load_lds(
      (const __attribute__((address_space(1))) unsigned int*)g,
      (__attribute__((address_space(3))) unsigned int*)l, 16, 0, 0);
}

static __device__ __forceinline__ u16x8 pack8(f32x4 a, f32x4 b) {
  u16x8 r;
  r[0] = f2b(a[0]); r[1] = f2b(a[1]); r[2] = f2b(a[2]); r[3] = f2b(a[3]);
  r[4] = f2b(b[0]); r[5] = f2b(b[1]); r[6] = f2b(b[2]); r[7] = f2b(b[3]);
  return r;
}

// ---------------------------------------------------------------------------
// mask (B,L,L) int32 -> bit pack (1 bit per element)
// ---------------------------------------------------------------------------
__global__ __launch_bounds__(256)
void maskpack_k(const int* __restrict__ mask, u64* __restrict__ mb) {
  const int lane = threadIdx.x & 63;
  const int gw = (blockIdx.x * 256 + threadIdx.x) >> 6;
  const int nw = (gridDim.x * 256) >> 6;
  const int NCH = NB * NL * NL / 64;
  for (int c = gw; c < NCH; c += nw) {
    int v = mask[(size_t)c * 64 + lane];
    u64 bal = __ballot(v != 0);
    if (lane == 0) mb[c] = bal;
  }
}

// ---------------------------------------------------------------------------
// GEMM: out[m][n] = sum_k A[m][k] * W[n][k] + bias[n]
// BM=128, BN=64, BK=64; 4 waves, each 64x32 out (acc 4x2 frags).
// MODE 0: bf16 out at (b,h,l,d); MODE 1: bf16 out at (b,h,d,l); MODE 2: f32 (m,n)
// ---------------------------------------------------------------------------
template<typename TA, int MODE>
__global__ __launch_bounds__(256)
void gemm_k(const TA* __restrict__ A, const float* __restrict__ W,
            const float* __restrict__ bias, void* __restrict__ outp,
            int M, int N, int K)
{
  __shared__ __align__(16) u16 lA[128 * 64];
  __shared__ __align__(16) u16 lB[64 * 64];
  const int tid = threadIdx.x;
  const int lane = tid & 63, wid = tid >> 6;
  const int wr = wid >> 1, wc = wid & 1;
  const int lrow = lane & 15, lgrp = lane >> 4;
  const int mbase = blockIdx.y * 128, nbase = blockIdx.x * 64;

  f32x4 acc[4][2] = {};

  for (int k0 = 0; k0 < K; k0 += 64) {
    __syncthreads();
    // stage A (128 x 64)
    if constexpr (sizeof(TA) == 4) {
#pragma unroll
      for (int i = 0; i < 4; ++i) {
        int o = i * 8192 + tid * 32;          // byte offset in f32-tile (256B rows)
        int r = o >> 8, c = (o & 255) >> 2;   // c: element col, multiple of 8
        const float* src = (const float*)A + (size_t)(mbase + r) * K + k0 + c;
        f32x4 v0 = *reinterpret_cast<const f32x4*>(src);
        f32x4 v1 = *reinterpret_cast<const f32x4*>(src + 4);
        *reinterpret_cast<u16x8*>((char*)lA + swz(r, c * 2)) = pack8(v0, v1);
      }
    } else {
#pragma unroll
      for (int i = 0; i < 4; ++i) {
        int o = i * 4096 + tid * 16;          // byte offset in bf16-tile (128B rows)
        int r = o >> 7, cb = o & 127;
        u16x8 v = *reinterpret_cast<const u16x8*>((const u16*)A + (size_t)(mbase + r) * K + k0 + cb / 2);
        *reinterpret_cast<u16x8*>((char*)lA + swz(r, cb)) = v;
      }
    }
    // stage W (64 x 64), always f32
#pragma unroll
    for (int i = 0; i < 2; ++i) {
      int o = i * 8192 + tid * 32;
      int r = o >> 8, c = (o & 255) >> 2;
      const float* src = W + (size_t)(nbase + r) * K + k0 + c;
      f32x4 v0 = *reinterpret_cast<const f32x4*>(src);
      f32x4 v1 = *reinterpret_cast<const f32x4*>(src + 4);
      *reinterpret_cast<u16x8*>((char*)lB + swz(r, c * 2)) = pack8(v0, v1);
    }
    __syncthreads();

#pragma unroll
    for (int ks = 0; ks < 2; ++ks) {
      s16x8 af[4], bf2[2];
#pragma unroll
      for (int mt = 0; mt < 4; ++mt)
        af[mt] = *reinterpret_cast<const s16x8*>((char*)lA + swz(wr * 64 + mt * 16 + lrow, ks * 64 + lgrp * 16));
#pragma unroll
      for (int nt = 0; nt < 2; ++nt)
        bf2[nt] = *reinterpret_cast<const s16x8*>((char*)lB + swz(wc * 32 + nt * 16 + lrow, ks * 64 + lgrp * 16));
#pragma unroll
      for (int mt = 0; mt < 4; ++mt)
#pragma unroll
        for (int nt = 0; nt < 2; ++nt)
          acc[mt][nt] = __builtin_amdgcn_mfma_f32_16x16x32_bf16(af[mt], bf2[nt], acc[mt][nt], 0, 0, 0);
    }
  }

  // epilogue: D layout col=lane&15 (n), row=lgrp*4+rg (m)
#pragma unroll
  for (int mt = 0; mt < 4; ++mt) {
#pragma unroll
    for (int nt = 0; nt < 2; ++nt) {
      int n = nbase + wc * 32 + nt * 16 + lrow;
      float bv = bias[n];
      int m0 = mbase + wr * 64 + mt * 16 + lgrp * 4;
      f32x4 a = acc[mt][nt];
      if constexpr (MODE == 1) {
        int b = m0 >> 11, l0 = m0 & 2047;
        int h = n >> 6, d = n & 63;
        u16x4 ov;
#pragma unroll
        for (int rg = 0; rg < 4; ++rg) ov[rg] = f2b(a[rg] + bv);
        *reinterpret_cast<u16x4*>((u16*)outp + ((size_t)((b * NH + h) * NDT + d)) * NL + l0) = ov;
      } else if constexpr (MODE == 0) {
#pragma unroll
        for (int rg = 0; rg < 4; ++rg) {
          int m = m0 + rg;
          int b = m >> 11, l = m & 2047;
          int h = n >> 6, d = n & 63;
          ((u16*)outp)[((size_t)((b * NH + h) * NL + l)) * NDT + d] = f2b(a[rg] + bv);
        }
      } else {
#pragma unroll
        for (int rg = 0; rg < 4; ++rg)
          ((float*)outp)[(size_t)(m0 + rg) * N + n] = a[rg] + bv;
      }
    }
  }
}

// ---------------------------------------------------------------------------
// Flash attention, swapped-operand S^T scheme.
// q,k: (B*H, L, 64) bf16; vt: (B*H, 64, L) bf16; mb: bitmask; bias f32; ao bf16 (B*L, 1024)
// Block: (b,h,qt) 64 q-rows, 4 waves x 16 rows. One barrier per kv-tile,
// K/V via global_load_lds double-buffer, bias/mask reg-prefetched 1 tile ahead.
// ---------------------------------------------------------------------------
__global__ __launch_bounds__(256)
void attn_k(const u16* __restrict__ q, const u16* __restrict__ k,
            const u16* __restrict__ vt, const u64* __restrict__ mb,
            const float* __restrict__ bias, u16* __restrict__ ao)
{
  __shared__ __align__(16) u16 kl2[2][64 * 64];
  __shared__ __align__(16) u16 vl2[2][64 * 64];
  __shared__ __align__(16) u16 pl[4][16 * 64];

  const int tid = threadIdx.x;
  const int lane = tid & 63, w = tid >> 6;
  const int lrow = lane & 15, lgrp = lane >> 4;
  const int bid = blockIdx.x;
  const int b = bid & 1;                 // b innermost: both batches share bias tile in L3
  const int h = (bid >> 1) & (NH - 1);
  const int qt = bid >> 5;
  const int bh = b * NH + h;
  const int qbase = qt * 64;
  const int qrow = qbase + w * 16 + lrow;   // this lane's q-row

  // Q as B-operand: col=lane&15=qrow, k=lgrp*8+j
  s16x8 qf[2];
#pragma unroll
  for (int ks = 0; ks < 2; ++ks)
    qf[ks] = *reinterpret_cast<const s16x8*>(q + ((size_t)bh * NL + qrow) * NDT + ks * 32 + lgrp * 8);

  f32x4 o4[4] = {};            // o4[dt][rg]: d = dt*16+lgrp*4+rg, col=qrow (lane-local stats!)
  float mrun = -3.0e38f, lrun = 0.f;

  const u64* mrow = mb + ((size_t)b * NL + qrow) * (NL / 64);
  const float* brow = bias + ((size_t)h * NL + qrow) * NL;
  u16* pw = pl[w];

  f32x4 bA[4], bB[4];
  u64 mA, mB;

#define LOADPF(BP, MM, KK) do {                                               \
  _Pragma("unroll") for (int nt = 0; nt < 4; ++nt)                            \
    BP[nt] = *reinterpret_cast<const f32x4*>(brow + (KK) + nt * 16 + lgrp * 4); \
  MM = mrow[(KK) >> 6];                                                       \
} while (0)

#define STAGEKV(KK, KD, VD) do {                                              \
  const char* ksrc = (const char*)(k + ((size_t)bh * NL + (KK)) * NDT);       \
  _Pragma("unroll") for (int i = 0; i < 2; ++i) {                             \
    int o = i * 4096 + w * 1024 + lane * 16;                                  \
    int r = o >> 7; int cb = (o & 127) ^ ((r & 7) << 4);                      \
    gl16(ksrc + r * 128 + cb, (char*)(KD) + i * 4096 + w * 1024);             \
    gl16((const char*)vt + (((size_t)bh * NDT + r) * NL + (KK)) * 2 + cb,     \
         (char*)(VD) + i * 4096 + w * 1024);                                  \
  }                                                                           \
} while (0)

#define TILE(KD, VD, BP, MM) do {                                             \
  float sv[4][4];                                                             \
  _Pragma("unroll") for (int nt = 0; nt < 4; ++nt) {                          \
    f32x4 s = {};                                                             \
    _Pragma("unroll") for (int ks = 0; ks < 2; ++ks) {                        \
      s16x8 kf = *reinterpret_cast<const s16x8*>((char*)(KD) + swz(nt * 16 + lrow, ks * 64 + lgrp * 16)); \
      s = __builtin_amdgcn_mfma_f32_16x16x32_bf16(kf, qf[ks], s, 0, 0, 0);    \
    }                                                                         \
    _Pragma("unroll") for (int rg = 0; rg < 4; ++rg) {                        \
      int sh = nt * 16 + lgrp * 4 + rg;                                       \
      float bz = BP[nt][rg];                                                  \
      sv[nt][rg] = ((MM >> sh) & 1ull) ? s[rg] * 0.125f + bz : bz - 10000.0f; \
    }                                                                         \
  }                                                                           \
  float mx = sv[0][0];                                                        \
  _Pragma("unroll") for (int nt = 0; nt < 4; ++nt)                            \
    _Pragma("unroll") for (int rg = 0; rg < 4; ++rg) mx = fmaxf(mx, sv[nt][rg]); \
  mx = fmaxf(mx, __shfl_xor(mx, 16)); mx = fmaxf(mx, __shfl_xor(mx, 32));     \
  float mnew = fmaxf(mrun, mx);                                               \
  float alpha = __expf(mrun - mnew); mrun = mnew;                             \
  float rs = 0.f;                                                             \
  _Pragma("unroll") for (int nt = 0; nt < 4; ++nt)                            \
    _Pragma("unroll") for (int rg = 0; rg < 4; ++rg) {                        \
      float p = __expf(sv[nt][rg] - mnew); sv[nt][rg] = p; rs += p;           \
    }                                                                         \
  rs += __shfl_xor(rs, 16); rs += __shfl_xor(rs, 32);                         \
  lrun = lrun * alpha + rs;                                                   \
  _Pragma("unroll") for (int dt = 0; dt < 4; ++dt)                            \
    _Pragma("unroll") for (int rg = 0; rg < 4; ++rg) o4[dt][rg] *= alpha;     \
  _Pragma("unroll") for (int nt = 0; nt < 4; ++nt) {                          \
    u16x4 pk;                                                                 \
    _Pragma("unroll") for (int rg = 0; rg < 4; ++rg) pk[rg] = f2b(sv[nt][rg]); \
    *reinterpret_cast<u16x4*>((char*)pw + swz(lrow, nt * 32 + lgrp * 8)) = pk; \
  }                                                                           \
  s16x8 pa0 = *reinterpret_cast<const s16x8*>((char*)pw + swz(lrow, lgrp * 16)); \
  s16x8 pa1 = *reinterpret_cast<const s16x8*>((char*)pw + swz(lrow, 64 + lgrp * 16)); \
  _Pragma("unroll") for (int dt = 0; dt < 4; ++dt) {                          \
    s16x8 vf0 = *reinterpret_cast<const s16x8*>((char*)(VD) + swz(dt * 16 + lrow, lgrp * 16)); \
    o4[dt] = __builtin_amdgcn_mfma_f32_16x16x32_bf16(vf0, pa0, o4[dt], 0, 0, 0); \
    s16x8 vf1 = *reinterpret_cast<const s16x8*>((char*)(VD) + swz(dt * 16 + lrow, 64 + lgrp * 16)); \
    o4[dt] = __builtin_amdgcn_mfma_f32_16x16x32_bf16(vf1, pa1, o4[dt], 0, 0, 0); \
  }                                                                           \
} while (0)

  STAGEKV(0, kl2[0], vl2[0]);
  LOADPF(bA, mA, 0);

  for (int tt = 0; tt < NL / 64; tt += 2) {
    __syncthreads();                       // tile tt staged; buf1 free
    STAGEKV((tt + 1) * 64, kl2[1], vl2[1]);
    LOADPF(bB, mB, (tt + 1) * 64);
    TILE(kl2[0], vl2[0], bA, mA);
    __syncthreads();                       // tile tt+1 staged; buf0 free
    if (tt + 2 < NL / 64) {
      STAGEKV((tt + 2) * 64, kl2[0], vl2[0]);
      LOADPF(bA, mA, (tt + 2) * 64);
    }
    TILE(kl2[1], vl2[1], bB, mB);
  }

  // normalize + write: lane qrow fixed; d = dt*16+lgrp*4+rg
  float inv = 1.0f / lrun;
#pragma unroll
  for (int dt = 0; dt < 4; ++dt) {
    u16x4 ov;
#pragma unroll
    for (int rg = 0; rg < 4; ++rg) ov[rg] = f2b(o4[dt][rg] * inv);
    *reinterpret_cast<u16x4*>(ao + ((size_t)(b * NL + qrow)) * ND + h * NDT + dt * 16 + lgrp * 4) = ov;
  }
#undef LOADPF
#undef STAGEKV
#undef TILE
}

extern "C" void kernel_launch(void* const* d_in, const int* in_sizes, int n_in,
                              void* d_out, int out_size, void* d_ws, size_t ws_size,
                              hipStream_t stream)
{
  const float* Q    = (const float*)d_in[0];
  const float* K    = (const float*)d_in[1];
  const float* V    = (const float*)d_in[2];
  const int*   mask = (const int*)d_in[3];
  const float* bias = (const float*)d_in[4];
  const float* Wq   = (const float*)d_in[5];
  const float* bq   = (const float*)d_in[6];
  const float* Wk   = (const float*)d_in[7];
  const float* bk   = (const float*)d_in[8];
  const float* Wv   = (const float*)d_in[9];
  const float* bv   = (const float*)d_in[10];
  const float* Wo   = (const float*)d_in[11];
  const float* bo   = (const float*)d_in[12];

  const size_t SZ = (size_t)NB * NH * NL * NDT;   // 4.19M elems (bf16)
  u16* qb  = (u16*)d_ws;
  u16* kb  = qb + SZ;
  u16* vtb = kb + SZ;
  u16* aob = vtb + SZ;
  u64* mbit = (u64*)(aob + SZ);

  dim3 blk(256);
  dim3 gproj(ND / 64, (NB * NL) / 128);

  maskpack_k<<<dim3(1024), blk, 0, stream>>>(mask, mbit);

  gemm_k<float, 0><<<gproj, blk, 0, stream>>>(Q, Wq, bq, qb,  NB * NL, ND, ND);
  gemm_k<float, 0><<<gproj, blk, 0, stream>>>(K, Wk, bk, kb,  NB * NL, ND, ND);
  gemm_k<float, 1><<<gproj, blk, 0, stream>>>(V, Wv, bv, vtb, NB * NL, ND, ND);

  attn_k<<<dim3(NB * NH * (NL / 64)), blk, 0, stream>>>(qb, kb, vtb, mbit, bias, aob);

  gemm_k<u16, 2><<<gproj, blk, 0, stream>>>(aob, Wo, bo, d_out, NB * NL, ND, ND);
}

// Round 3
// 399.155 us; speedup vs baseline: 1.0459x; 1.0272x over previous
//
#include <hip/hip_runtime.h>
#include <hip/hip_bf16.h>

#define NB 2
#define NL 2048
#define ND 1024
#define NH 16
#define NDT 64
#define SZE ((size_t)NB * NL * ND)   // 4194304
#define WSZE ((size_t)ND * ND)       // 1048576

typedef unsigned short u16;
typedef unsigned int u32;
typedef unsigned long long u64;

typedef __attribute__((ext_vector_type(8))) short s16x8;
typedef __attribute__((ext_vector_type(4))) float f32x4;
typedef __attribute__((ext_vector_type(4))) u16 u16x4;
typedef __attribute__((ext_vector_type(8))) u16 u16x8;

// f32 -> bf16 (RNE)
static __device__ __forceinline__ u16 f2b(float f) {
  union { float f; u32 u; } x; x.f = f;
  u32 r = x.u + 0x7fffu + ((x.u >> 16) & 1u);
  return (u16)(r >> 16);
}

// XOR-swizzled byte offset within a [rows][64] bf16 tile (128B rows)
static __device__ __forceinline__ int swz(int r, int cb) {
  return r * 128 + (cb ^ ((r & 7) << 4));
}

// async global->LDS 16B (dest: wave-uniform base + lane*16)
static __device__ __forceinline__ void gl16(const void* g, void* l) {
  __builtin_amdgcn_global_load_lds(
      (const __attribute__((address_space(1))) unsigned int*)g,
      (__attribute__((address_space(3))) unsigned int*)l, 16, 0, 0);
}

static __device__ __forceinline__ u16x8 pack8(f32x4 a, f32x4 b) {
  u16x8 r;
  r[0] = f2b(a[0]); r[1] = f2b(a[1]); r[2] = f2b(a[2]); r[3] = f2b(a[3]);
  r[4] = f2b(b[0]); r[5] = f2b(b[1]); r[6] = f2b(b[2]); r[7] = f2b(b[3]);
  return r;
}

// pinned prefetch loads: asm volatile so the compiler cannot sink or remat
// them; results become valid after the next __syncthreads() (vmcnt(0)).
static __device__ __forceinline__ f32x4 ldg_v4(const float* p) {
  f32x4 r;
  asm volatile("global_load_dwordx4 %0, %1, off" : "=v"(r) : "v"(p) : "memory");
  return r;
}
static __device__ __forceinline__ u64 ldg_v2(const u64* p) {
  u64 r;
  asm volatile("global_load_dwordx2 %0, %1, off" : "=v"(r) : "v"(p) : "memory");
  return r;
}

// ---------------------------------------------------------------------------
// f32 -> bf16 convert: z=0..2 inputs Q,K,V -> cin; z=3..6 weights -> cw
// ---------------------------------------------------------------------------
__global__ __launch_bounds__(256)
void conv_k(const float* __restrict__ q, const float* __restrict__ k,
            const float* __restrict__ v, const float* __restrict__ wq,
            const float* __restrict__ wk, const float* __restrict__ wv,
            const float* __restrict__ wo, u16* __restrict__ cin,
            u16* __restrict__ cw)
{
  const int z = blockIdx.z;
  const float* s; u16* d; size_t n;
  if (z < 3) { s = (z == 0) ? q : (z == 1) ? k : v; d = cin + (size_t)z * SZE; n = SZE; }
  else { int m = z - 3; s = (m == 0) ? wq : (m == 1) ? wk : (m == 2) ? wv : wo; d = cw + (size_t)m * WSZE; n = WSZE; }
  size_t i = ((size_t)blockIdx.x * 256 + threadIdx.x) * 8;
  if (i >= n) return;
  f32x4 a = *reinterpret_cast<const f32x4*>(s + i);
  f32x4 b = *reinterpret_cast<const f32x4*>(s + i + 4);
  *reinterpret_cast<u16x8*>(d + i) = pack8(a, b);
}

// ---------------------------------------------------------------------------
// mask (B,L,L) int32 -> bit pack
// ---------------------------------------------------------------------------
__global__ __launch_bounds__(256)
void maskpack_k(const int* __restrict__ mask, u64* __restrict__ mb) {
  const int lane = threadIdx.x & 63;
  const int gw = (blockIdx.x * 256 + threadIdx.x) >> 6;
  const int nw = (gridDim.x * 256) >> 6;
  const int NCH = NB * NL * NL / 64;
  for (int c = gw; c < NCH; c += nw) {
    int v = mask[(size_t)c * 64 + lane];
    u64 bal = __ballot(v != 0);
    if (lane == 0) mb[c] = bal;
  }
}

// ---------------------------------------------------------------------------
// GEMM, 64x64 tile, BK=64, glds dbuf, 1 barrier/K-step. All operands bf16.
// FINAL=0: z=blockIdx.z picks (A,W,bias); out bf16 q/k at (b,h,l,d), v at (b,h,d,l)
// FINAL=1: out f32 (m,n), W = Wbase + 3*WSZE
// ---------------------------------------------------------------------------
template<int FINAL>
__global__ __launch_bounds__(256, 4)
void gemm_k(const u16* __restrict__ Abase, const u16* __restrict__ Wbase,
            const float* __restrict__ b0, const float* __restrict__ b1,
            const float* __restrict__ b2, void* __restrict__ outp)
{
  __shared__ __align__(16) u16 lA[2][64 * 64];
  __shared__ __align__(16) u16 lB[2][64 * 64];
  const int tid = threadIdx.x, lane = tid & 63, w = tid >> 6;
  const int wr = w >> 1, wc = w & 1, lrow = lane & 15, lgrp = lane >> 4;
  const int z = FINAL ? 0 : blockIdx.z;
  const u16* A = Abase + (FINAL ? (size_t)0 : (size_t)z * SZE);
  const u16* W = Wbase + (FINAL ? 3 * WSZE : (size_t)z * WSZE);
  const float* bias = FINAL ? b0 : (z == 0 ? b0 : (z == 1) ? b1 : b2);
  const int mbase = blockIdx.y * 64, nbase = blockIdx.x * 64;

  f32x4 acc[2][2] = {};

#define GSTAGE(BUF, T) do {                                                   \
  const int k0 = (T) * 64;                                                    \
  _Pragma("unroll") for (int i = 0; i < 2; ++i) {                             \
    int o = w * 2048 + i * 1024 + lane * 16;                                  \
    int r = o >> 7, cb = o & 127;                                             \
    int cs = cb ^ ((r & 7) << 4);                                             \
    gl16((const char*)(A + (size_t)(mbase + r) * ND + k0) + cs,               \
         (char*)lA[BUF] + w * 2048 + i * 1024);                               \
    gl16((const char*)(W + (size_t)(nbase + r) * ND + k0) + cs,               \
         (char*)lB[BUF] + w * 2048 + i * 1024);                               \
  }                                                                           \
} while (0)

#define GCOMP(BUF) do {                                                       \
  _Pragma("unroll") for (int ks = 0; ks < 2; ++ks) {                          \
    s16x8 af[2], bf[2];                                                       \
    _Pragma("unroll") for (int t = 0; t < 2; ++t) {                           \
      af[t] = *reinterpret_cast<const s16x8*>((char*)lA[BUF] + swz(wr * 32 + t * 16 + lrow, ks * 64 + lgrp * 16)); \
      bf[t] = *reinterpret_cast<const s16x8*>((char*)lB[BUF] + swz(wc * 32 + t * 16 + lrow, ks * 64 + lgrp * 16)); \
    }                                                                         \
    _Pragma("unroll") for (int mt = 0; mt < 2; ++mt)                          \
      _Pragma("unroll") for (int nt = 0; nt < 2; ++nt)                        \
        acc[mt][nt] = __builtin_amdgcn_mfma_f32_16x16x32_bf16(af[mt], bf[nt], acc[mt][nt], 0, 0, 0); \
  }                                                                           \
} while (0)

  GSTAGE(0, 0);
  __syncthreads();
  int cur = 0;
#pragma unroll 1
  for (int t = 0; t < 15; ++t) {
    GSTAGE(cur ^ 1, t + 1);
    GCOMP(cur);
    __syncthreads();
    cur ^= 1;
  }
  GCOMP(cur);

#pragma unroll
  for (int mt = 0; mt < 2; ++mt) {
#pragma unroll
    for (int nt = 0; nt < 2; ++nt) {
      int n = nbase + wc * 32 + nt * 16 + lrow;
      float bv = bias[n];
      int m0 = mbase + wr * 32 + mt * 16 + lgrp * 4;
      f32x4 a = acc[mt][nt];
      if constexpr (FINAL) {
#pragma unroll
        for (int rg = 0; rg < 4; ++rg)
          ((float*)outp)[(size_t)(m0 + rg) * ND + n] = a[rg] + bv;
      } else {
        int h = n >> 6, d = n & 63;
        if (z == 2) {
          int b = m0 >> 11, l0 = m0 & 2047;
          u16x4 ov;
#pragma unroll
          for (int rg = 0; rg < 4; ++rg) ov[rg] = f2b(a[rg] + bv);
          *reinterpret_cast<u16x4*>((u16*)outp + 2 * SZE + ((size_t)(b * NH + h) * NDT + d) * NL + l0) = ov;
        } else {
#pragma unroll
          for (int rg = 0; rg < 4; ++rg) {
            int m = m0 + rg;
            int b = m >> 11, l = m & 2047;
            ((u16*)outp)[(size_t)z * SZE + ((size_t)(b * NH + h) * NL + l) * NDT + d] = f2b(a[rg] + bv);
          }
        }
      }
    }
  }
#undef GSTAGE
#undef GCOMP
}

// ---------------------------------------------------------------------------
// Flash attention, swapped-operand S^T scheme, asm-pinned bias/mask prefetch.
// ---------------------------------------------------------------------------
__global__ __launch_bounds__(256, 4)
void attn_k(const u16* __restrict__ q, const u16* __restrict__ k,
            const u16* __restrict__ vt, const u64* __restrict__ mb,
            const float* __restrict__ bias, u16* __restrict__ ao)
{
  __shared__ __align__(16) u16 kl2[2][64 * 64];
  __shared__ __align__(16) u16 vl2[2][64 * 64];
  __shared__ __align__(16) u16 pl[4][16 * 64];

  const int tid = threadIdx.x;
  const int lane = tid & 63, w = tid >> 6;
  const int lrow = lane & 15, lgrp = lane >> 4;
  const int bid = blockIdx.x;
  const int b = bid & 1;
  const int h = (bid >> 1) & (NH - 1);
  const int qt = bid >> 5;
  const int bh = b * NH + h;
  const int qbase = qt * 64;
  const int qrow = qbase + w * 16 + lrow;

  s16x8 qf[2];
#pragma unroll
  for (int ks = 0; ks < 2; ++ks)
    qf[ks] = *reinterpret_cast<const s16x8*>(q + ((size_t)bh * NL + qrow) * NDT + ks * 32 + lgrp * 8);

  f32x4 o4[4] = {};
  float mrun = -3.0e38f, lrun = 0.f;

  const u64* mrow = mb + ((size_t)b * NL + qrow) * (NL / 64);
  const float* brow = bias + ((size_t)h * NL + qrow) * NL;
  u16* pw = pl[w];

  f32x4 bA[4], bB[4];
  u64 mA, mB;

#define LOADPF(BP, MM, KK) do {                                               \
  _Pragma("unroll") for (int nt = 0; nt < 4; ++nt)                            \
    BP[nt] = ldg_v4(brow + (KK) + nt * 16 + lgrp * 4);                        \
  MM = ldg_v2(mrow + ((KK) >> 6));                                            \
} while (0)

#define STAGEKV(KK, KD, VD) do {                                              \
  const char* ksrc = (const char*)(k + ((size_t)bh * NL + (KK)) * NDT);       \
  _Pragma("unroll") for (int i = 0; i < 2; ++i) {                             \
    int o = i * 4096 + w * 1024 + lane * 16;                                  \
    int r = o >> 7; int cb = (o & 127) ^ ((r & 7) << 4);                      \
    gl16(ksrc + r * 128 + cb, (char*)(KD) + i * 4096 + w * 1024);             \
    gl16((const char*)vt + (((size_t)bh * NDT + r) * NL + (KK)) * 2 + cb,     \
         (char*)(VD) + i * 4096 + w * 1024);                                  \
  }                                                                           \
} while (0)

#define TILE(KD, VD, BP, MM) do {                                             \
  float sv[4][4];                                                             \
  _Pragma("unroll") for (int nt = 0; nt < 4; ++nt) {                          \
    f32x4 s = {};                                                             \
    _Pragma("unroll") for (int ks = 0; ks < 2; ++ks) {                        \
      s16x8 kf = *reinterpret_cast<const s16x8*>((char*)(KD) + swz(nt * 16 + lrow, ks * 64 + lgrp * 16)); \
      s = __builtin_amdgcn_mfma_f32_16x16x32_bf16(kf, qf[ks], s, 0, 0, 0);    \
    }                                                                         \
    _Pragma("unroll") for (int rg = 0; rg < 4; ++rg) {                        \
      int sh = nt * 16 + lgrp * 4 + rg;                                       \
      float bz = BP[nt][rg];                                                  \
      sv[nt][rg] = ((MM >> sh) & 1ull) ? s[rg] * 0.125f + bz : bz - 10000.0f; \
    }                                                                         \
  }                                                                           \
  float mx = sv[0][0];                                                        \
  _Pragma("unroll") for (int nt = 0; nt < 4; ++nt)                            \
    _Pragma("unroll") for (int rg = 0; rg < 4; ++rg) mx = fmaxf(mx, sv[nt][rg]); \
  mx = fmaxf(mx, __shfl_xor(mx, 16)); mx = fmaxf(mx, __shfl_xor(mx, 32));     \
  float mnew = fmaxf(mrun, mx);                                               \
  float alpha = __expf(mrun - mnew); mrun = mnew;                             \
  float rs = 0.f;                                                             \
  _Pragma("unroll") for (int nt = 0; nt < 4; ++nt)                            \
    _Pragma("unroll") for (int rg = 0; rg < 4; ++rg) {                        \
      float p = __expf(sv[nt][rg] - mnew); sv[nt][rg] = p; rs += p;           \
    }                                                                         \
  rs += __shfl_xor(rs, 16); rs += __shfl_xor(rs, 32);                         \
  lrun = lrun * alpha + rs;                                                   \
  _Pragma("unroll") for (int dt = 0; dt < 4; ++dt)                            \
    _Pragma("unroll") for (int rg = 0; rg < 4; ++rg) o4[dt][rg] *= alpha;     \
  _Pragma("unroll") for (int nt = 0; nt < 4; ++nt) {                          \
    u16x4 pk;                                                                 \
    _Pragma("unroll") for (int rg = 0; rg < 4; ++rg) pk[rg] = f2b(sv[nt][rg]); \
    *reinterpret_cast<u16x4*>((char*)pw + swz(lrow, nt * 32 + lgrp * 8)) = pk; \
  }                                                                           \
  s16x8 pa0 = *reinterpret_cast<const s16x8*>((char*)pw + swz(lrow, lgrp * 16)); \
  s16x8 pa1 = *reinterpret_cast<const s16x8*>((char*)pw + swz(lrow, 64 + lgrp * 16)); \
  _Pragma("unroll") for (int dt = 0; dt < 4; ++dt) {                          \
    s16x8 vf0 = *reinterpret_cast<const s16x8*>((char*)(VD) + swz(dt * 16 + lrow, lgrp * 16)); \
    o4[dt] = __builtin_amdgcn_mfma_f32_16x16x32_bf16(vf0, pa0, o4[dt], 0, 0, 0); \
    s16x8 vf1 = *reinterpret_cast<const s16x8*>((char*)(VD) + swz(dt * 16 + lrow, 64 + lgrp * 16)); \
    o4[dt] = __builtin_amdgcn_mfma_f32_16x16x32_bf16(vf1, pa1, o4[dt], 0, 0, 0); \
  }                                                                           \
} while (0)

  STAGEKV(0, kl2[0], vl2[0]);
  LOADPF(bA, mA, 0);

#pragma unroll 1
  for (int tt = 0; tt < NL / 64; tt += 2) {
    __syncthreads();
    STAGEKV((tt + 1) * 64, kl2[1], vl2[1]);
    LOADPF(bB, mB, (tt + 1) * 64);
    TILE(kl2[0], vl2[0], bA, mA);
    __syncthreads();
    if (tt + 2 < NL / 64) {
      STAGEKV((tt + 2) * 64, kl2[0], vl2[0]);
      LOADPF(bA, mA, (tt + 2) * 64);
    }
    TILE(kl2[1], vl2[1], bB, mB);
  }

  float inv = 1.0f / lrun;
#pragma unroll
  for (int dt = 0; dt < 4; ++dt) {
    u16x4 ov;
#pragma unroll
    for (int rg = 0; rg < 4; ++rg) ov[rg] = f2b(o4[dt][rg] * inv);
    *reinterpret_cast<u16x4*>(ao + ((size_t)(b * NL + qrow)) * ND + h * NDT + dt * 16 + lgrp * 4) = ov;
  }
#undef LOADPF
#undef STAGEKV
#undef TILE
}

extern "C" void kernel_launch(void* const* d_in, const int* in_sizes, int n_in,
                              void* d_out, int out_size, void* d_ws, size_t ws_size,
                              hipStream_t stream)
{
  const float* Q    = (const float*)d_in[0];
  const float* K    = (const float*)d_in[1];
  const float* V    = (const float*)d_in[2];
  const int*   mask = (const int*)d_in[3];
  const float* bias = (const float*)d_in[4];
  const float* Wq   = (const float*)d_in[5];
  const float* bq   = (const float*)d_in[6];
  const float* Wk   = (const float*)d_in[7];
  const float* bk   = (const float*)d_in[8];
  const float* Wv   = (const float*)d_in[9];
  const float* bv   = (const float*)d_in[10];
  const float* Wo   = (const float*)d_in[11];
  const float* bo   = (const float*)d_in[12];

  u16* cin  = (u16*)d_ws;              // 3*SZE   (bf16 Q,K,V inputs)
  u16* cw   = cin + 3 * SZE;           // 4*WSZE  (bf16 weights)
  u16* qkv  = cw + 4 * WSZE;           // 3*SZE   (projected q, k, vt)
  u64* mbit = (u64*)(qkv + 3 * SZE);   // 1 MB
  u16* aob  = cin;                     // alias: cin dead after projections

  dim3 blk(256);

  conv_k<<<dim3(2048, 1, 7), blk, 0, stream>>>(Q, K, V, Wq, Wk, Wv, Wo, cin, cw);
  maskpack_k<<<dim3(1024), blk, 0, stream>>>(mask, mbit);

  gemm_k<0><<<dim3(ND / 64, (NB * NL) / 64, 3), blk, 0, stream>>>(cin, cw, bq, bk, bv, qkv);

  attn_k<<<dim3(NB * NH * (NL / 64)), blk, 0, stream>>>(qkv, qkv + SZE, qkv + 2 * SZE, mbit, bias, aob);

  gemm_k<1><<<dim3(ND / 64, (NB * NL) / 64), blk, 0, stream>>>(aob, cw, bo, bo, bo, d_out);
}

// Round 4
// 245.775 us; speedup vs baseline: 1.6986x; 1.6241x over previous
//
#include <hip/hip_runtime.h>
#include <hip/hip_bf16.h>

#define NB 2
#define NL 2048
#define ND 1024
#define NH 16
#define NDT 64
#define SZE ((size_t)NB * NL * ND)   // 4194304
#define WSZE ((size_t)ND * ND)       // 1048576

typedef unsigned short u16;
typedef unsigned int u32;
typedef unsigned long long u64;

typedef __attribute__((ext_vector_type(8))) short s16x8;
typedef __attribute__((ext_vector_type(4))) float f32x4;
typedef __attribute__((ext_vector_type(4))) u16 u16x4;
typedef __attribute__((ext_vector_type(8))) u16 u16x8;

// f32 -> bf16 (RNE)
static __device__ __forceinline__ u16 f2b(float f) {
  union { float f; u32 u; } x; x.f = f;
  u32 r = x.u + 0x7fffu + ((x.u >> 16) & 1u);
  return (u16)(r >> 16);
}

// XOR-swizzled byte offset within a [rows][64] bf16 tile (128B rows)
static __device__ __forceinline__ int swz(int r, int cb) {
  return r * 128 + (cb ^ ((r & 7) << 4));
}

// async global->LDS 16B (dest: wave-uniform base + lane*16)
static __device__ __forceinline__ void gl16(const void* g, void* l) {
  __builtin_amdgcn_global_load_lds(
      (const __attribute__((address_space(1))) unsigned int*)g,
      (__attribute__((address_space(3))) unsigned int*)l, 16, 0, 0);
}

static __device__ __forceinline__ u16x8 pack8(f32x4 a, f32x4 b) {
  u16x8 r;
  r[0] = f2b(a[0]); r[1] = f2b(a[1]); r[2] = f2b(a[2]); r[3] = f2b(a[3]);
  r[4] = f2b(b[0]); r[5] = f2b(b[1]); r[6] = f2b(b[2]); r[7] = f2b(b[3]);
  return r;
}

// pinned 8B prefetch (2 VGPRs only; cannot be sunk/remat by compiler)
static __device__ __forceinline__ u64 ldg_v2(const u64* p) {
  u64 r;
  asm volatile("global_load_dwordx2 %0, %1, off" : "=v"(r) : "v"(p) : "memory");
  return r;
}

// ---------------------------------------------------------------------------
// f32 -> bf16 convert: z=0..2 inputs Q,K,V -> cin; z=3..6 weights -> cw
// ---------------------------------------------------------------------------
__global__ __launch_bounds__(256)
void conv_k(const float* __restrict__ q, const float* __restrict__ k,
            const float* __restrict__ v, const float* __restrict__ wq,
            const float* __restrict__ wk, const float* __restrict__ wv,
            const float* __restrict__ wo, u16* __restrict__ cin,
            u16* __restrict__ cw)
{
  const int z = blockIdx.z;
  const float* s; u16* d; size_t n;
  if (z < 3) { s = (z == 0) ? q : (z == 1) ? k : v; d = cin + (size_t)z * SZE; n = SZE; }
  else { int m = z - 3; s = (m == 0) ? wq : (m == 1) ? wk : (m == 2) ? wv : wo; d = cw + (size_t)m * WSZE; n = WSZE; }
  size_t i = ((size_t)blockIdx.x * 256 + threadIdx.x) * 8;
  if (i >= n) return;
  f32x4 a = *reinterpret_cast<const f32x4*>(s + i);
  f32x4 b = *reinterpret_cast<const f32x4*>(s + i + 4);
  *reinterpret_cast<u16x8*>(d + i) = pack8(a, b);
}

// ---------------------------------------------------------------------------
// mask (B,L,L) int32 -> bit pack: mb[(b*NL+qrow)*32 + kt], bit = k in tile
// ---------------------------------------------------------------------------
__global__ __launch_bounds__(256)
void maskpack_k(const int* __restrict__ mask, u64* __restrict__ mb) {
  const int lane = threadIdx.x & 63;
  const int gw = (blockIdx.x * 256 + threadIdx.x) >> 6;
  const int nw = (gridDim.x * 256) >> 6;
  const int NCH = NB * NL * NL / 64;
  for (int c = gw; c < NCH; c += nw) {
    int v = mask[(size_t)c * 64 + lane];
    u64 bal = __ballot(v != 0);
    if (lane == 0) mb[c] = bal;
  }
}

// ---------------------------------------------------------------------------
// GEMM, 128x128 tile, BK=64, glds dbuf, 1 barrier/K-step. bf16 operands.
// FINAL=0: z picks (A,W,bias); q/k out bf16 (b,h,l,d), v out bf16 (b,h,d,l)
// FINAL=1: out f32 (m,n), W = Wbase + 3*WSZE
// ---------------------------------------------------------------------------
template<int FINAL>
__global__ __launch_bounds__(256, 2)
void gemm_k(const u16* __restrict__ Abase, const u16* __restrict__ Wbase,
            const float* __restrict__ b0, const float* __restrict__ b1,
            const float* __restrict__ b2, void* __restrict__ outp)
{
  __shared__ __align__(16) u16 lA[2][128 * 64];
  __shared__ __align__(16) u16 lB[2][128 * 64];
  const int tid = threadIdx.x, lane = tid & 63, w = tid >> 6;
  const int wr = w >> 1, wc = w & 1, lrow = lane & 15, lgrp = lane >> 4;
  const int z = FINAL ? 0 : blockIdx.z;
  const u16* A = Abase + (FINAL ? (size_t)0 : (size_t)z * SZE);
  const u16* W = Wbase + (FINAL ? 3 * WSZE : (size_t)z * WSZE);
  const float* bias = FINAL ? b0 : (z == 0 ? b0 : (z == 1) ? b1 : b2);
  const int mbase = blockIdx.y * 128, nbase = blockIdx.x * 128;

  f32x4 acc[4][4] = {};

#define GSTAGE(BUF, T) do {                                                   \
  const int k0 = (T) * 64;                                                    \
  _Pragma("unroll") for (int i = 0; i < 4; ++i) {                             \
    int r = i * 32 + w * 8 + (lane >> 3);                                     \
    int cb = ((lane & 7) << 4) ^ ((r & 7) << 4);                              \
    gl16((const char*)(A + (size_t)(mbase + r) * ND + k0) + cb,               \
         (char*)lA[BUF] + i * 4096 + w * 1024);                               \
    gl16((const char*)(W + (size_t)(nbase + r) * ND + k0) + cb,               \
         (char*)lB[BUF] + i * 4096 + w * 1024);                               \
  }                                                                           \
} while (0)

#define GCOMP(BUF) do {                                                       \
  _Pragma("unroll") for (int ks = 0; ks < 2; ++ks) {                          \
    s16x8 af[4], bf[4];                                                       \
    _Pragma("unroll") for (int t = 0; t < 4; ++t) {                           \
      af[t] = *reinterpret_cast<const s16x8*>((char*)lA[BUF] + swz(wr * 64 + t * 16 + lrow, ks * 64 + lgrp * 16)); \
      bf[t] = *reinterpret_cast<const s16x8*>((char*)lB[BUF] + swz(wc * 64 + t * 16 + lrow, ks * 64 + lgrp * 16)); \
    }                                                                         \
    _Pragma("unroll") for (int mt = 0; mt < 4; ++mt)                          \
      _Pragma("unroll") for (int nt = 0; nt < 4; ++nt)                        \
        acc[mt][nt] = __builtin_amdgcn_mfma_f32_16x16x32_bf16(af[mt], bf[nt], acc[mt][nt], 0, 0, 0); \
  }                                                                           \
} while (0)

  GSTAGE(0, 0);
  __syncthreads();
  int cur = 0;
#pragma unroll 1
  for (int t = 0; t < 15; ++t) {
    GSTAGE(cur ^ 1, t + 1);
    GCOMP(cur);
    __syncthreads();
    cur ^= 1;
  }
  GCOMP(cur);

#pragma unroll
  for (int mt = 0; mt < 4; ++mt) {
#pragma unroll
    for (int nt = 0; nt < 4; ++nt) {
      int n = nbase + wc * 64 + nt * 16 + lrow;
      float bv = bias[n];
      int m0 = mbase + wr * 64 + mt * 16 + lgrp * 4;
      f32x4 a = acc[mt][nt];
      if constexpr (FINAL) {
#pragma unroll
        for (int rg = 0; rg < 4; ++rg)
          ((float*)outp)[(size_t)(m0 + rg) * ND + n] = a[rg] + bv;
      } else {
        int h = n >> 6, d = n & 63;
        if (z == 2) {
          int b = m0 >> 11, l0 = m0 & 2047;
          u16x4 ov;
#pragma unroll
          for (int rg = 0; rg < 4; ++rg) ov[rg] = f2b(a[rg] + bv);
          *reinterpret_cast<u16x4*>((u16*)outp + 2 * SZE + ((size_t)(b * NH + h) * NDT + d) * NL + l0) = ov;
        } else {
#pragma unroll
          for (int rg = 0; rg < 4; ++rg) {
            int m = m0 + rg;
            int b = m >> 11, l = m & 2047;
            ((u16*)outp)[(size_t)z * SZE + ((size_t)(b * NH + h) * NL + l) * NDT + d] = f2b(a[rg] + bv);
          }
        }
      }
    }
  }
#undef GSTAGE
#undef GCOMP
}

// ---------------------------------------------------------------------------
// Flash attention, swapped-operand S^T; K/V/bias all staged via glds dbuf.
// ---------------------------------------------------------------------------
__global__ __launch_bounds__(256, 2)
void attn_k(const u16* __restrict__ q, const u16* __restrict__ k,
            const u16* __restrict__ vt, const u64* __restrict__ mb,
            const float* __restrict__ bias, u16* __restrict__ ao)
{
  __shared__ __align__(16) u16 kl2[2][64 * 64];
  __shared__ __align__(16) u16 vl2[2][64 * 64];
  __shared__ __align__(16) float bl2[2][64 * 64];
  __shared__ __align__(16) u16 pl[4][16 * 64];

  const int tid = threadIdx.x;
  const int lane = tid & 63, w = tid >> 6;
  const int lrow = lane & 15, lgrp = lane >> 4;
  const int bid = blockIdx.x;
  const int b = bid & 1;
  const int h = (bid >> 1) & (NH - 1);
  const int qt = bid >> 5;
  const int bh = b * NH + h;
  const int qbase = qt * 64;
  const int qrow = qbase + w * 16 + lrow;
  const int rr = w * 16 + lrow;          // local q-row for bias reads

  s16x8 qf[2];
#pragma unroll
  for (int ks = 0; ks < 2; ++ks)
    qf[ks] = *reinterpret_cast<const s16x8*>(q + ((size_t)bh * NL + qrow) * NDT + ks * 32 + lgrp * 8);

  f32x4 o4[4] = {};
  float mrun = -3.0e38f, lrun = 0.f;

  const u64* mrow = mb + ((size_t)b * NL + qrow) * (NL / 64);
  u16* pw = pl[w];
  u64 mA, mB;

#define STAGEA(KK, KD, VD, BD) do {                                           \
  const char* ksrc = (const char*)(k + ((size_t)bh * NL + (KK)) * NDT);       \
  _Pragma("unroll") for (int i = 0; i < 2; ++i) {                             \
    int o = i * 4096 + w * 1024 + lane * 16;                                  \
    int r = o >> 7; int cb = (o & 127) ^ ((r & 7) << 4);                      \
    gl16(ksrc + r * 128 + cb, (char*)(KD) + i * 4096 + w * 1024);             \
    gl16((const char*)vt + (((size_t)bh * NDT + r) * NL + (KK)) * 2 + cb,     \
         (char*)(VD) + i * 4096 + w * 1024);                                  \
  }                                                                           \
  _Pragma("unroll") for (int i = 0; i < 4; ++i) {                             \
    int r = i * 16 + w * 4 + lgrp;                                            \
    int c = lane & 15;                                                        \
    gl16((const char*)(bias + ((size_t)h * NL + qbase + r) * NL + (KK)) +     \
             ((c ^ (r & 15)) << 4),                                           \
         (char*)(BD) + i * 4096 + w * 1024);                                  \
  }                                                                           \
} while (0)

#define TILE(KD, VD, BD, MM) do {                                             \
  float sv[4][4];                                                             \
  _Pragma("unroll") for (int nt = 0; nt < 4; ++nt) {                          \
    f32x4 s = {};                                                             \
    _Pragma("unroll") for (int ks = 0; ks < 2; ++ks) {                        \
      s16x8 kf = *reinterpret_cast<const s16x8*>((char*)(KD) + swz(nt * 16 + lrow, ks * 64 + lgrp * 16)); \
      s = __builtin_amdgcn_mfma_f32_16x16x32_bf16(kf, qf[ks], s, 0, 0, 0);    \
    }                                                                         \
    f32x4 bf = *reinterpret_cast<const f32x4*>((const char*)(BD) + rr * 256 + ((((nt << 2) + lgrp) ^ lrow) << 4)); \
    _Pragma("unroll") for (int rg = 0; rg < 4; ++rg) {                        \
      int sh = nt * 16 + lgrp * 4 + rg;                                       \
      sv[nt][rg] = ((MM >> sh) & 1ull) ? s[rg] * 0.125f + bf[rg] : bf[rg] - 10000.0f; \
    }                                                                         \
  }                                                                           \
  float mx = sv[0][0];                                                        \
  _Pragma("unroll") for (int nt = 0; nt < 4; ++nt)                            \
    _Pragma("unroll") for (int rg = 0; rg < 4; ++rg) mx = fmaxf(mx, sv[nt][rg]); \
  mx = fmaxf(mx, __shfl_xor(mx, 16)); mx = fmaxf(mx, __shfl_xor(mx, 32));     \
  float mnew = fmaxf(mrun, mx);                                               \
  float alpha = __expf(mrun - mnew); mrun = mnew;                             \
  float rs = 0.f;                                                             \
  _Pragma("unroll") for (int nt = 0; nt < 4; ++nt)                            \
    _Pragma("unroll") for (int rg = 0; rg < 4; ++rg) {                        \
      float p = __expf(sv[nt][rg] - mnew); sv[nt][rg] = p; rs += p;           \
    }                                                                         \
  rs += __shfl_xor(rs, 16); rs += __shfl_xor(rs, 32);                         \
  lrun = lrun * alpha + rs;                                                   \
  _Pragma("unroll") for (int dt = 0; dt < 4; ++dt)                            \
    _Pragma("unroll") for (int rg = 0; rg < 4; ++rg) o4[dt][rg] *= alpha;     \
  _Pragma("unroll") for (int nt = 0; nt < 4; ++nt) {                          \
    u16x4 pk;                                                                 \
    _Pragma("unroll") for (int rg = 0; rg < 4; ++rg) pk[rg] = f2b(sv[nt][rg]); \
    *reinterpret_cast<u16x4*>((char*)pw + swz(lrow, nt * 32 + lgrp * 8)) = pk; \
  }                                                                           \
  s16x8 pa0 = *reinterpret_cast<const s16x8*>((char*)pw + swz(lrow, lgrp * 16)); \
  s16x8 pa1 = *reinterpret_cast<const s16x8*>((char*)pw + swz(lrow, 64 + lgrp * 16)); \
  _Pragma("unroll") for (int dt = 0; dt < 4; ++dt) {                          \
    s16x8 vf0 = *reinterpret_cast<const s16x8*>((char*)(VD) + swz(dt * 16 + lrow, lgrp * 16)); \
    o4[dt] = __builtin_amdgcn_mfma_f32_16x16x32_bf16(vf0, pa0, o4[dt], 0, 0, 0); \
    s16x8 vf1 = *reinterpret_cast<const s16x8*>((char*)(VD) + swz(dt * 16 + lrow, 64 + lgrp * 16)); \
    o4[dt] = __builtin_amdgcn_mfma_f32_16x16x32_bf16(vf1, pa1, o4[dt], 0, 0, 0); \
  }                                                                           \
} while (0)

  STAGEA(0, kl2[0], vl2[0], bl2[0]);
  mA = ldg_v2(mrow + 0);
  __syncthreads();

#pragma unroll 1
  for (int tt = 0; tt < NL / 64; tt += 2) {
    STAGEA((tt + 1) * 64, kl2[1], vl2[1], bl2[1]);
    mB = ldg_v2(mrow + tt + 1);
    TILE(kl2[0], vl2[0], bl2[0], mA);
    __syncthreads();
    if (tt + 2 < NL / 64) {
      STAGEA((tt + 2) * 64, kl2[0], vl2[0], bl2[0]);
      mA = ldg_v2(mrow + tt + 2);
    }
    TILE(kl2[1], vl2[1], bl2[1], mB);
    __syncthreads();
  }

  float inv = 1.0f / lrun;
#pragma unroll
  for (int dt = 0; dt < 4; ++dt) {
    u16x4 ov;
#pragma unroll
    for (int rg = 0; rg < 4; ++rg) ov[rg] = f2b(o4[dt][rg] * inv);
    *reinterpret_cast<u16x4*>(ao + ((size_t)(b * NL + qrow)) * ND + h * NDT + dt * 16 + lgrp * 4) = ov;
  }
#undef STAGEA
#undef TILE
}

extern "C" void kernel_launch(void* const* d_in, const int* in_sizes, int n_in,
                              void* d_out, int out_size, void* d_ws, size_t ws_size,
                              hipStream_t stream)
{
  const float* Q    = (const float*)d_in[0];
  const float* K    = (const float*)d_in[1];
  const float* V    = (const float*)d_in[2];
  const int*   mask = (const int*)d_in[3];
  const float* bias = (const float*)d_in[4];
  const float* Wq   = (const float*)d_in[5];
  const float* bq   = (const float*)d_in[6];
  const float* Wk   = (const float*)d_in[7];
  const float* bk   = (const float*)d_in[8];
  const float* Wv   = (const float*)d_in[9];
  const float* bv   = (const float*)d_in[10];
  const float* Wo   = (const float*)d_in[11];
  const float* bo   = (const float*)d_in[12];

  u16* cin  = (u16*)d_ws;              // 3*SZE   (bf16 Q,K,V inputs)
  u16* cw   = cin + 3 * SZE;           // 4*WSZE  (bf16 weights)
  u16* qkv  = cw + 4 * WSZE;           // 3*SZE   (projected q, k, vt)
  u64* mbit = (u64*)(qkv + 3 * SZE);   // 1 MB
  u16* aob  = cin;                     // alias: cin dead after projections

  dim3 blk(256);

  conv_k<<<dim3(2048, 1, 7), blk, 0, stream>>>(Q, K, V, Wq, Wk, Wv, Wo, cin, cw);
  maskpack_k<<<dim3(1024), blk, 0, stream>>>(mask, mbit);

  gemm_k<0><<<dim3(ND / 128, (NB * NL) / 128, 3), blk, 0, stream>>>(cin, cw, bq, bk, bv, qkv);

  attn_k<<<dim3(NB * NH * (NL / 64)), blk, 0, stream>>>(qkv, qkv + SZE, qkv + 2 * SZE, mbit, bias, aob);

  gemm_k<1><<<dim3(ND / 128, (NB * NL) / 128), blk, 0, stream>>>(aob, cw, bo, bo, bo, d_out);
}